// Round 10
// baseline (300.003 us; speedup 1.0000x reference)
//
#include <hip/hip_runtime.h>
#include <math.h>

#define IN_DIM 128
#define HEADS 8
#define HID 16
#define OUT_DIM 40
#define NEG 0.2f
#define NSLICE 8

typedef short bf16x8 __attribute__((ext_vector_type(8)));
typedef float f32x4 __attribute__((ext_vector_type(4)));

__device__ __forceinline__ unsigned short f32_to_bf16_rne(float v) {
  unsigned u = __float_as_uint(v);
  return (unsigned short)((u + 0x7FFFu + ((u >> 16) & 1u)) >> 16);
}

// ---------------- CSR build (XCD-sliced: block b -> edge chunk b>>3, dst slice b&7) ----------------

__global__ void hist_k(const int* __restrict__ ei, int E0, int N, int snode,
                       int* __restrict__ deg) {
  int b = blockIdx.x;
  int slice = b & (NSLICE - 1);
  int e = (b >> 3) * 256 + threadIdx.x;
  int EP = E0 + N;
  if (e >= EP) return;
  int d = (e < E0) ? ei[E0 + e] : (e - E0);
  if (d / snode == slice) atomicAdd(&deg[d], 1);
}

__global__ __launch_bounds__(1024) void scanA_k(const int* __restrict__ deg, int* __restrict__ rp,
                                                int* __restrict__ bsum, int n) {
  __shared__ int wsum[16];
  int tid = threadIdx.x;
  int i = blockIdx.x * 1024 + tid;
  int lane = tid & 63, w = tid >> 6;
  int v = (i < n) ? deg[i] : 0;
  int x = v;
  #pragma unroll
  for (int off = 1; off < 64; off <<= 1) {
    int y = __shfl_up(x, off);
    if (lane >= off) x += y;
  }
  if (lane == 63) wsum[w] = x;
  __syncthreads();
  if (tid < 16) {
    int s = wsum[tid];
    #pragma unroll
    for (int off = 1; off < 16; off <<= 1) {
      int y = __shfl_up(s, off);
      if (tid >= off) s += y;
    }
    wsum[tid] = s;
  }
  __syncthreads();
  int woff = (w == 0) ? 0 : wsum[w - 1];
  if (i < n) rp[i] = woff + x - v;
  if (tid == 0) bsum[blockIdx.x] = wsum[15];
}

__global__ __launch_bounds__(1024) void scanB_k(int* __restrict__ bsum, int nb,
                                                int* __restrict__ rp, int n) {
  __shared__ int wsum[16];
  int tid = threadIdx.x;
  int lane = tid & 63, w = tid >> 6;
  int v = (tid < nb) ? bsum[tid] : 0;
  int x = v;
  #pragma unroll
  for (int off = 1; off < 64; off <<= 1) {
    int y = __shfl_up(x, off);
    if (lane >= off) x += y;
  }
  if (lane == 63) wsum[w] = x;
  __syncthreads();
  if (tid < 16) {
    int s = wsum[tid];
    #pragma unroll
    for (int off = 1; off < 16; off <<= 1) {
      int y = __shfl_up(s, off);
      if (tid >= off) s += y;
    }
    wsum[tid] = s;
  }
  __syncthreads();
  int woff = (w == 0) ? 0 : wsum[w - 1];
  if (tid < nb) bsum[tid] = woff + x - v;
  if (tid == 0) rp[n] = wsum[15];
}

__global__ __launch_bounds__(1024) void scanC_k(int* __restrict__ rp, const int* __restrict__ bsum,
                                                int* __restrict__ cnt, int n) {
  int i = blockIdx.x * 1024 + threadIdx.x;
  if (i < n) {
    int v = rp[i] + bsum[blockIdx.x];
    rp[i] = v;
    cnt[i] = v;
  }
}

__global__ void scatter_k(const int* __restrict__ ei, int E0, int N, int snode,
                          int* __restrict__ cnt, int* __restrict__ csr_src) {
  int b = blockIdx.x;
  int slice = b & (NSLICE - 1);
  int e = (b >> 3) * 256 + threadIdx.x;
  int EP = E0 + N;
  if (e >= EP) return;
  int d = (e < E0) ? ei[E0 + e] : (e - E0);
  if (d / snode != slice) return;
  int s = (e < E0) ? ei[e] : d;
  int pos = atomicAdd(&cnt[d], 1);
  csr_src[pos] = s;
}

// ---------------- prep: zero deg + pack W1 (hi/lo bf16) + pack W2 (bf16, folded att cols) ----------------
__global__ void prep_k(const float* __restrict__ W1, const float* __restrict__ as1,
                       const float* __restrict__ ad1, const float* __restrict__ W2,
                       const float* __restrict__ as2, const float* __restrict__ ad2,
                       unsigned short* __restrict__ whi, unsigned short* __restrict__ wlo,
                       unsigned short* __restrict__ w2p, int* __restrict__ deg, int N) {
  int t = blockIdx.x * 256 + threadIdx.x;
  if (t < N) deg[t] = 0;
  if (t < 18432) {
    int j = t & 7, lane = (t >> 3) & 63, kc = (t >> 9) & 3, ct = t >> 11;
    int k = kc * 32 + (lane >> 4) * 8 + j;
    int col = lane & 15;
    float v;
    if (ct < 8) {
      v = W1[k * 128 + ct * 16 + col];
    } else {
      int h = col & 7;
      const float* att = (col < 8) ? as1 : ad1;
      float s = 0.f;
      #pragma unroll
      for (int d = 0; d < 16; ++d) s += W1[k * 128 + h * 16 + d] * att[h * 16 + d];
      v = s;
    }
    unsigned u = __float_as_uint(v);
    unsigned hi = (u + 0x7FFFu + ((u >> 16) & 1u)) >> 16;
    float rem = v - __uint_as_float(hi << 16);
    unsigned ur = __float_as_uint(rem);
    unsigned lo = (ur + 0x7FFFu + ((ur >> 16) & 1u)) >> 16;
    whi[t] = (unsigned short)hi;
    wlo[t] = (unsigned short)lo;
  } else if (t < 18432 + 6144) {
    int u2 = t - 18432;
    int j = u2 & 7, lane = (u2 >> 3) & 63, kc = (u2 >> 9) & 3, ct = u2 >> 11;  // ct 0..2
    int k = kc * 32 + (lane >> 4) * 8 + j;
    int col = ct * 16 + (lane & 15);
    float v;
    if (col < OUT_DIM) {
      v = W2[k * OUT_DIM + col];
    } else if (col < 42) {
      const float* att = (col == OUT_DIM) ? as2 : ad2;
      float s = 0.f;
      #pragma unroll 8
      for (int d = 0; d < OUT_DIM; ++d) s += W2[k * OUT_DIM + d] * att[d];
      v = s;
    } else {
      v = 0.f;
    }
    w2p[u2] = f32_to_bf16_rne(v);
  }
}

// ---------------- GEMM1 via MFMA (split-bf16), fused a1s/a1d; h1 stored bf16 ----------------
__global__ __launch_bounds__(256) void gemm1_mfma_k(
    const float* __restrict__ x, const unsigned short* __restrict__ whi,
    const unsigned short* __restrict__ wlo,
    unsigned short* __restrict__ h1, float* __restrict__ a1s, float* __restrict__ a1d, int N) {
  int w = threadIdx.x >> 6, lane = threadIdx.x & 63;
  int quad = lane >> 4, l15 = lane & 15;
  int row = blockIdx.x * 64 + w * 16 + l15;
  int rowc = (row < N) ? row : (N - 1);

  f32x4 acc[9];
  #pragma unroll
  for (int t = 0; t < 9; ++t) acc[t] = (f32x4){0.f, 0.f, 0.f, 0.f};

  const float* xr = x + (size_t)rowc * 128 + quad * 8;
  #pragma unroll
  for (int kc = 0; kc < 4; ++kc) {
    f32x4 a0 = *reinterpret_cast<const f32x4*>(xr + kc * 32);
    f32x4 a1 = *reinterpret_cast<const f32x4*>(xr + kc * 32 + 4);
    float av[8] = {a0.x, a0.y, a0.z, a0.w, a1.x, a1.y, a1.z, a1.w};
    bf16x8 ahi, alo;
    #pragma unroll
    for (int j = 0; j < 8; ++j) {
      unsigned u = __float_as_uint(av[j]);
      unsigned hi = (u + 0x7FFFu + ((u >> 16) & 1u)) >> 16;
      float rem = av[j] - __uint_as_float(hi << 16);
      unsigned ur = __float_as_uint(rem);
      unsigned lo = (ur + 0x7FFFu + ((ur >> 16) & 1u)) >> 16;
      ahi[j] = (short)hi;
      alo[j] = (short)lo;
    }
    #pragma unroll
    for (int ct = 0; ct < 9; ++ct) {
      bf16x8 bh = *reinterpret_cast<const bf16x8*>(whi + ((size_t)(ct * 4 + kc) * 64 + lane) * 8);
      bf16x8 bl = *reinterpret_cast<const bf16x8*>(wlo + ((size_t)(ct * 4 + kc) * 64 + lane) * 8);
      acc[ct] = __builtin_amdgcn_mfma_f32_16x16x32_bf16(ahi, bh, acc[ct], 0, 0, 0);
      acc[ct] = __builtin_amdgcn_mfma_f32_16x16x32_bf16(ahi, bl, acc[ct], 0, 0, 0);
      acc[ct] = __builtin_amdgcn_mfma_f32_16x16x32_bf16(alo, bh, acc[ct], 0, 0, 0);
    }
  }
  int rbase = blockIdx.x * 64 + w * 16 + quad * 4;
  #pragma unroll
  for (int reg = 0; reg < 4; ++reg) {
    int r = rbase + reg;
    if (r < N) {
      #pragma unroll
      for (int ct = 0; ct < 8; ++ct)
        h1[(size_t)r * 128 + ct * 16 + l15] = f32_to_bf16_rne(acc[ct][reg]);
      float v = acc[8][reg];
      if (l15 < 8) a1s[r * 8 + l15] = v;
      else         a1d[r * 8 + (l15 - 8)] = v;
    }
  }
}

// ---------------- w1: per-node normalized softmax weights (f32, CSR order) ----------------
// wave per node: 8 edge-slots x 8 heads; each exp computed by exactly one lane.
__global__ __launch_bounds__(256) void w1_k(
    const int* __restrict__ rp, const int* __restrict__ csr,
    const float* __restrict__ a1s, const float* __restrict__ a1d,
    float* __restrict__ w1n, int N) {
  int wid = threadIdx.x >> 6, lane = threadIdx.x & 63;
  int n = blockIdx.x * 4 + wid;
  if (n >= N) return;
  int rs = rp[n], re = rp[n + 1];
  int slot = lane >> 3, hw = lane & 7;
  float adn = a1d[n * 8 + hw];
  float sw = 0.f;
  for (int i0 = rs; i0 < re; i0 += 8) {
    int idx = i0 + slot;
    if (idx < re) {
      int s = csr[idx];
      float e = a1s[s * 8 + hw] + adn;
      e = fmaxf(e, NEG * e);
      sw += __expf(e);
    }
  }
  sw += __shfl_xor(sw, 8);
  sw += __shfl_xor(sw, 16);
  sw += __shfl_xor(sw, 32);
  float inv = 1.f / (sw + 1e-16f);
  for (int i0 = rs; i0 < re; i0 += 8) {
    int idx = i0 + slot;
    if (idx < re) {
      int s = csr[idx];
      float e = a1s[s * 8 + hw] + adn;
      e = fmaxf(e, NEG * e);
      w1n[(size_t)idx * 8 + hw] = __expf(e) * inv;
    }
  }
}

// ---------------- Layer-1 aggregation: slim loop (precomputed normalized weights) ----------------
__global__ __launch_bounds__(256) void agg1_k(
    const int* __restrict__ row_ptr, const int* __restrict__ csr_src,
    const float* __restrict__ w1n,
    const unsigned* __restrict__ h1u, const float* __restrict__ bias1,
    unsigned* __restrict__ vrowp, int N) {
  int wid = threadIdx.x >> 6;
  int lane = threadIdx.x & 63;
  int n = blockIdx.x * 4 + wid;
  if (n >= N) return;

  int rs = row_ptr[n], re = row_ptr[n + 1];
  int h = lane >> 3;

  float accx = 0.f, accy = 0.f;
  int i = rs;
  for (; i + 8 <= re; i += 8) {
    int s0 = csr_src[i],     s1 = csr_src[i + 1], s2 = csr_src[i + 2], s3 = csr_src[i + 3];
    int s4 = csr_src[i + 4], s5 = csr_src[i + 5], s6 = csr_src[i + 6], s7 = csr_src[i + 7];
    float w0 = w1n[(size_t)(i + 0) * 8 + h];
    float w1 = w1n[(size_t)(i + 1) * 8 + h];
    float w2 = w1n[(size_t)(i + 2) * 8 + h];
    float w3 = w1n[(size_t)(i + 3) * 8 + h];
    float w4 = w1n[(size_t)(i + 4) * 8 + h];
    float w5 = w1n[(size_t)(i + 5) * 8 + h];
    float w6 = w1n[(size_t)(i + 6) * 8 + h];
    float w7 = w1n[(size_t)(i + 7) * 8 + h];
    unsigned u0 = h1u[(size_t)s0 * 64 + lane];
    unsigned u1 = h1u[(size_t)s1 * 64 + lane];
    unsigned u2 = h1u[(size_t)s2 * 64 + lane];
    unsigned u3 = h1u[(size_t)s3 * 64 + lane];
    unsigned u4 = h1u[(size_t)s4 * 64 + lane];
    unsigned u5 = h1u[(size_t)s5 * 64 + lane];
    unsigned u6 = h1u[(size_t)s6 * 64 + lane];
    unsigned u7 = h1u[(size_t)s7 * 64 + lane];
    accx += w0 * __uint_as_float(u0 << 16) + w1 * __uint_as_float(u1 << 16)
          + w2 * __uint_as_float(u2 << 16) + w3 * __uint_as_float(u3 << 16)
          + w4 * __uint_as_float(u4 << 16) + w5 * __uint_as_float(u5 << 16)
          + w6 * __uint_as_float(u6 << 16) + w7 * __uint_as_float(u7 << 16);
    accy += w0 * __uint_as_float(u0 & 0xFFFF0000u) + w1 * __uint_as_float(u1 & 0xFFFF0000u)
          + w2 * __uint_as_float(u2 & 0xFFFF0000u) + w3 * __uint_as_float(u3 & 0xFFFF0000u)
          + w4 * __uint_as_float(u4 & 0xFFFF0000u) + w5 * __uint_as_float(u5 & 0xFFFF0000u)
          + w6 * __uint_as_float(u6 & 0xFFFF0000u) + w7 * __uint_as_float(u7 & 0xFFFF0000u);
  }
  for (; i + 4 <= re; i += 4) {
    int s0 = csr_src[i], s1 = csr_src[i + 1], s2 = csr_src[i + 2], s3 = csr_src[i + 3];
    float w0 = w1n[(size_t)(i + 0) * 8 + h];
    float w1 = w1n[(size_t)(i + 1) * 8 + h];
    float w2 = w1n[(size_t)(i + 2) * 8 + h];
    float w3 = w1n[(size_t)(i + 3) * 8 + h];
    unsigned u0 = h1u[(size_t)s0 * 64 + lane];
    unsigned u1 = h1u[(size_t)s1 * 64 + lane];
    unsigned u2 = h1u[(size_t)s2 * 64 + lane];
    unsigned u3 = h1u[(size_t)s3 * 64 + lane];
    accx += w0 * __uint_as_float(u0 << 16) + w1 * __uint_as_float(u1 << 16)
          + w2 * __uint_as_float(u2 << 16) + w3 * __uint_as_float(u3 << 16);
    accy += w0 * __uint_as_float(u0 & 0xFFFF0000u) + w1 * __uint_as_float(u1 & 0xFFFF0000u)
          + w2 * __uint_as_float(u2 & 0xFFFF0000u) + w3 * __uint_as_float(u3 & 0xFFFF0000u);
  }
  for (; i < re; ++i) {
    int s = csr_src[i];
    float w = w1n[(size_t)i * 8 + h];
    unsigned u = h1u[(size_t)s * 64 + lane];
    accx += w * __uint_as_float(u << 16);
    accy += w * __uint_as_float(u & 0xFFFF0000u);
  }
  float2 b = *reinterpret_cast<const float2*>(bias1 + 2 * lane);
  float vx = accx + b.x;
  float vy = accy + b.y;
  vx = (vx > 0.f) ? vx : (__expf(vx) - 1.f);
  vy = (vy > 0.f) ? vy : (__expf(vy) - 1.f);
  unsigned packed = (unsigned)f32_to_bf16_rne(vx) | ((unsigned)f32_to_bf16_rne(vy) << 16);
  vrowp[(size_t)n * 64 + lane] = packed;
}

// ---------------- GEMM2 via MFMA: h2 = ELU(vrow) @ W2 (+ folded a2s/a2d cols) ----------------
__global__ __launch_bounds__(256) void gemm2_mfma_k(
    const unsigned short* __restrict__ vrow, const unsigned short* __restrict__ w2p,
    unsigned short* __restrict__ h2, float* __restrict__ a2s, float* __restrict__ a2d, int N) {
  int w = threadIdx.x >> 6, lane = threadIdx.x & 63;
  int quad = lane >> 4, l15 = lane & 15;
  int row = blockIdx.x * 64 + w * 16 + l15;
  int rowc = (row < N) ? row : (N - 1);

  f32x4 acc[3];
  #pragma unroll
  for (int t = 0; t < 3; ++t) acc[t] = (f32x4){0.f, 0.f, 0.f, 0.f};

  const unsigned short* vr = vrow + (size_t)rowc * 128 + quad * 8;
  #pragma unroll
  for (int kc = 0; kc < 4; ++kc) {
    bf16x8 a = *reinterpret_cast<const bf16x8*>(vr + kc * 32);
    #pragma unroll
    for (int ct = 0; ct < 3; ++ct) {
      bf16x8 bfrag = *reinterpret_cast<const bf16x8*>(w2p + ((size_t)(ct * 4 + kc) * 64 + lane) * 8);
      acc[ct] = __builtin_amdgcn_mfma_f32_16x16x32_bf16(a, bfrag, acc[ct], 0, 0, 0);
    }
  }
  int rbase = blockIdx.x * 64 + w * 16 + quad * 4;
  #pragma unroll
  for (int reg = 0; reg < 4; ++reg) {
    int r = rbase + reg;
    if (r < N) {
      #pragma unroll
      for (int ct = 0; ct < 3; ++ct) {
        int col = ct * 16 + l15;
        float v = acc[ct][reg];
        if (col < OUT_DIM)       h2[(size_t)r * 64 + col] = f32_to_bf16_rne(v);
        else if (col == OUT_DIM) a2s[r] = v;
        else if (col == 41)      a2d[r] = v;
      }
    }
  }
}

// ---------------- w2: per-node normalized weights (single head) ----------------
__global__ __launch_bounds__(256) void w2_k(
    const int* __restrict__ rp, const int* __restrict__ csr,
    const float* __restrict__ a2s, const float* __restrict__ a2d,
    float* __restrict__ w2n, int N) {
  int wid = threadIdx.x >> 6, lane = threadIdx.x & 63;
  int n = blockIdx.x * 4 + wid;
  if (n >= N) return;
  int rs = rp[n], re = rp[n + 1];
  float adn = a2d[n];
  float sw = 0.f;
  for (int i = rs + lane; i < re; i += 64) {
    int s = csr[i];
    float e = a2s[s] + adn;
    e = fmaxf(e, NEG * e);
    sw += __expf(e);
  }
  #pragma unroll
  for (int off = 32; off > 0; off >>= 1) sw += __shfl_xor(sw, off);
  float inv = 1.f / (sw + 1e-16f);
  for (int i = rs + lane; i < re; i += 64) {
    int s = csr[i];
    float e = a2s[s] + adn;
    e = fmaxf(e, NEG * e);
    w2n[i] = __expf(e) * inv;
  }
}

// ---------------- Layer-2 aggregation + log_softmax: slim loop ----------------
__global__ __launch_bounds__(256) void agg2_k(
    const int* __restrict__ row_ptr, const int* __restrict__ csr_src,
    const float* __restrict__ w2n,
    const unsigned short* __restrict__ h2, const float* __restrict__ bias2,
    float* __restrict__ out, int N) {
  int wid = threadIdx.x >> 6;
  int lane = threadIdx.x & 63;
  int n = blockIdx.x * 4 + wid;
  if (n >= N) return;

  int rs = row_ptr[n], re = row_ptr[n + 1];
  bool act = lane < OUT_DIM;
  float acc = 0.f;
  int i = rs;
  for (; i + 8 <= re; i += 8) {
    int s0 = csr_src[i],     s1 = csr_src[i + 1], s2 = csr_src[i + 2], s3 = csr_src[i + 3];
    int s4 = csr_src[i + 4], s5 = csr_src[i + 5], s6 = csr_src[i + 6], s7 = csr_src[i + 7];
    float w0 = w2n[i],     w1 = w2n[i + 1], w2 = w2n[i + 2], w3 = w2n[i + 3];
    float w4 = w2n[i + 4], w5 = w2n[i + 5], w6 = w2n[i + 6], w7 = w2n[i + 7];
    unsigned g0 = h2[(size_t)s0 * 64 + lane];
    unsigned g1 = h2[(size_t)s1 * 64 + lane];
    unsigned g2 = h2[(size_t)s2 * 64 + lane];
    unsigned g3 = h2[(size_t)s3 * 64 + lane];
    unsigned g4 = h2[(size_t)s4 * 64 + lane];
    unsigned g5 = h2[(size_t)s5 * 64 + lane];
    unsigned g6 = h2[(size_t)s6 * 64 + lane];
    unsigned g7 = h2[(size_t)s7 * 64 + lane];
    acc += w0 * __uint_as_float(g0 << 16) + w1 * __uint_as_float(g1 << 16)
         + w2 * __uint_as_float(g2 << 16) + w3 * __uint_as_float(g3 << 16)
         + w4 * __uint_as_float(g4 << 16) + w5 * __uint_as_float(g5 << 16)
         + w6 * __uint_as_float(g6 << 16) + w7 * __uint_as_float(g7 << 16);
  }
  for (; i + 4 <= re; i += 4) {
    int s0 = csr_src[i], s1 = csr_src[i + 1], s2 = csr_src[i + 2], s3 = csr_src[i + 3];
    float w0 = w2n[i], w1 = w2n[i + 1], w2 = w2n[i + 2], w3 = w2n[i + 3];
    unsigned g0 = h2[(size_t)s0 * 64 + lane];
    unsigned g1 = h2[(size_t)s1 * 64 + lane];
    unsigned g2 = h2[(size_t)s2 * 64 + lane];
    unsigned g3 = h2[(size_t)s3 * 64 + lane];
    acc += w0 * __uint_as_float(g0 << 16) + w1 * __uint_as_float(g1 << 16)
         + w2 * __uint_as_float(g2 << 16) + w3 * __uint_as_float(g3 << 16);
  }
  for (; i < re; ++i) {
    int s = csr_src[i];
    float w = w2n[i];
    unsigned g = h2[(size_t)s * 64 + lane];
    acc += w * __uint_as_float(g << 16);
  }
  float v = act ? (acc + bias2[lane]) : -1e30f;
  float vm = v;
  #pragma unroll
  for (int off = 32; off > 0; off >>= 1) vm = fmaxf(vm, __shfl_xor(vm, off));
  float ex = act ? __expf(v - vm) : 0.f;
  float es = ex;
  #pragma unroll
  for (int off = 32; off > 0; off >>= 1) es += __shfl_xor(es, off);
  if (act) out[(size_t)n * OUT_DIM + lane] = v - vm - __logf(es);
}

// ---------------- launch ----------------

extern "C" void kernel_launch(void* const* d_in, const int* in_sizes, int n_in,
                              void* d_out, int out_size, void* d_ws, size_t ws_size,
                              hipStream_t stream) {
  const float* x   = (const float*)d_in[0];
  const float* W1  = (const float*)d_in[1];
  const float* as1 = (const float*)d_in[2];
  const float* ad1 = (const float*)d_in[3];
  const float* b1  = (const float*)d_in[4];
  const float* W2  = (const float*)d_in[5];
  const float* as2 = (const float*)d_in[6];
  const float* ad2 = (const float*)d_in[7];
  const float* b2  = (const float*)d_in[8];
  const int*   ei  = (const int*)d_in[9];
  int N  = in_sizes[0] / IN_DIM;
  int E0 = in_sizes[9] / 2;
  int EP = E0 + N;
  int snode = (N + NSLICE - 1) / NSLICE;
  float* out = (float*)d_out;

  char* ws = (char*)d_ws;
  size_t off = 0;
  auto alloc = [&](size_t bytes) {
    char* p = ws + off;
    off += (bytes + 255) & ~size_t(255);
    return p;
  };
  unsigned short* h1   = (unsigned short*)alloc((size_t)N * 128 * 2);
  float* a1s  = (float*)alloc((size_t)N * 8 * 4);
  float* a1d  = (float*)alloc((size_t)N * 8 * 4);
  unsigned*       vrow = (unsigned*)alloc((size_t)N * 64 * 4);   // N x 128 bf16 packed
  unsigned short* h2   = (unsigned short*)alloc((size_t)N * 64 * 2);
  float* a2s  = (float*)alloc((size_t)N * 4);
  float* a2d  = (float*)alloc((size_t)N * 4);
  float* w1n  = (float*)alloc((size_t)EP * 8 * 4);
  float* w2n  = (float*)alloc((size_t)EP * 4);
  int*   deg  = (int*)alloc((size_t)N * 4);
  int*   cnt  = (int*)alloc((size_t)N * 4);
  int*   rp   = (int*)alloc((size_t)(N + 4) * 4);
  int*   bsum = (int*)alloc((size_t)1024 * 4);
  int*   csr  = (int*)alloc((size_t)EP * 4);
  unsigned short* whi = (unsigned short*)alloc((size_t)18432 * 2);
  unsigned short* wlo = (unsigned short*)alloc((size_t)18432 * 2);
  unsigned short* w2p = (unsigned short*)alloc((size_t)6144 * 2);

  int nb = (N + 1023) / 1024;
  int nchunk = (EP + 255) / 256;
  prep_k<<<(N + 255) / 256, 256, 0, stream>>>(W1, as1, ad1, W2, as2, ad2, whi, wlo, w2p, deg, N);
  hist_k<<<nchunk * NSLICE, 256, 0, stream>>>(ei, E0, N, snode, deg);
  scanA_k<<<nb, 1024, 0, stream>>>(deg, rp, bsum, N);
  scanB_k<<<1, 1024, 0, stream>>>(bsum, nb, rp, N);
  scanC_k<<<nb, 1024, 0, stream>>>(rp, bsum, cnt, N);
  scatter_k<<<nchunk * NSLICE, 256, 0, stream>>>(ei, E0, N, snode, cnt, csr);
  gemm1_mfma_k<<<(N + 63) / 64, 256, 0, stream>>>(x, whi, wlo, h1, a1s, a1d, N);
  w1_k<<<(N + 3) / 4, 256, 0, stream>>>(rp, csr, a1s, a1d, w1n, N);
  agg1_k<<<(N + 3) / 4, 256, 0, stream>>>(rp, csr, w1n, (const unsigned*)h1, b1, vrow, N);
  gemm2_mfma_k<<<(N + 63) / 64, 256, 0, stream>>>((const unsigned short*)vrow, w2p, h2, a2s, a2d, N);
  w2_k<<<(N + 3) / 4, 256, 0, stream>>>(rp, csr, a2s, a2d, w2n, N);
  agg2_k<<<(N + 3) / 4, 256, 0, stream>>>(rp, csr, w2n, h2, b2, out, N);
}

// Round 11
// 270.028 us; speedup vs baseline: 1.1110x; 1.1110x over previous
//
#include <hip/hip_runtime.h>
#include <math.h>

#define IN_DIM 128
#define HEADS 8
#define HID 16
#define OUT_DIM 40
#define NEG 0.2f
#define NSLICE 8

typedef short bf16x8 __attribute__((ext_vector_type(8)));
typedef float f32x4 __attribute__((ext_vector_type(4)));

__device__ __forceinline__ unsigned short f32_to_bf16_rne(float v) {
  unsigned u = __float_as_uint(v);
  return (unsigned short)((u + 0x7FFFu + ((u >> 16) & 1u)) >> 16);
}

// ---------------- CSR build (XCD-sliced: block b -> edge chunk b>>3, dst slice b&7) ----------------

__global__ void hist_k(const int* __restrict__ ei, int E0, int N, int snode,
                       int* __restrict__ deg) {
  int b = blockIdx.x;
  int slice = b & (NSLICE - 1);
  int e = (b >> 3) * 256 + threadIdx.x;
  int EP = E0 + N;
  if (e >= EP) return;
  int d = (e < E0) ? ei[E0 + e] : (e - E0);
  if (d / snode == slice) atomicAdd(&deg[d], 1);
}

__global__ __launch_bounds__(1024) void scanA_k(const int* __restrict__ deg, int* __restrict__ rp,
                                                int* __restrict__ bsum, int n) {
  __shared__ int wsum[16];
  int tid = threadIdx.x;
  int i = blockIdx.x * 1024 + tid;
  int lane = tid & 63, w = tid >> 6;
  int v = (i < n) ? deg[i] : 0;
  int x = v;
  #pragma unroll
  for (int off = 1; off < 64; off <<= 1) {
    int y = __shfl_up(x, off);
    if (lane >= off) x += y;
  }
  if (lane == 63) wsum[w] = x;
  __syncthreads();
  if (tid < 16) {
    int s = wsum[tid];
    #pragma unroll
    for (int off = 1; off < 16; off <<= 1) {
      int y = __shfl_up(s, off);
      if (tid >= off) s += y;
    }
    wsum[tid] = s;
  }
  __syncthreads();
  int woff = (w == 0) ? 0 : wsum[w - 1];
  if (i < n) rp[i] = woff + x - v;
  if (tid == 0) bsum[blockIdx.x] = wsum[15];
}

__global__ __launch_bounds__(1024) void scanB_k(int* __restrict__ bsum, int nb,
                                                int* __restrict__ rp, int n) {
  __shared__ int wsum[16];
  int tid = threadIdx.x;
  int lane = tid & 63, w = tid >> 6;
  int v = (tid < nb) ? bsum[tid] : 0;
  int x = v;
  #pragma unroll
  for (int off = 1; off < 64; off <<= 1) {
    int y = __shfl_up(x, off);
    if (lane >= off) x += y;
  }
  if (lane == 63) wsum[w] = x;
  __syncthreads();
  if (tid < 16) {
    int s = wsum[tid];
    #pragma unroll
    for (int off = 1; off < 16; off <<= 1) {
      int y = __shfl_up(s, off);
      if (tid >= off) s += y;
    }
    wsum[tid] = s;
  }
  __syncthreads();
  int woff = (w == 0) ? 0 : wsum[w - 1];
  if (tid < nb) bsum[tid] = woff + x - v;
  if (tid == 0) rp[n] = wsum[15];
}

__global__ __launch_bounds__(1024) void scanC_k(int* __restrict__ rp, const int* __restrict__ bsum,
                                                int* __restrict__ cnt, int n) {
  int i = blockIdx.x * 1024 + threadIdx.x;
  if (i < n) {
    int v = rp[i] + bsum[blockIdx.x];
    rp[i] = v;
    cnt[i] = v;
  }
}

__global__ void scatter_k(const int* __restrict__ ei, int E0, int N, int snode,
                          int* __restrict__ cnt, int* __restrict__ csr_src) {
  int b = blockIdx.x;
  int slice = b & (NSLICE - 1);
  int e = (b >> 3) * 256 + threadIdx.x;
  int EP = E0 + N;
  if (e >= EP) return;
  int d = (e < E0) ? ei[E0 + e] : (e - E0);
  if (d / snode != slice) return;
  int s = (e < E0) ? ei[e] : d;
  int pos = atomicAdd(&cnt[d], 1);
  csr_src[pos] = s;
}

// ---------------- prep: zero deg + pack W1 (hi/lo bf16) + pack W2 (bf16, folded att cols) ----------------
__global__ void prep_k(const float* __restrict__ W1, const float* __restrict__ as1,
                       const float* __restrict__ ad1, const float* __restrict__ W2,
                       const float* __restrict__ as2, const float* __restrict__ ad2,
                       unsigned short* __restrict__ whi, unsigned short* __restrict__ wlo,
                       unsigned short* __restrict__ w2p, int* __restrict__ deg, int N) {
  int t = blockIdx.x * 256 + threadIdx.x;
  if (t < N) deg[t] = 0;
  if (t < 18432) {
    int j = t & 7, lane = (t >> 3) & 63, kc = (t >> 9) & 3, ct = t >> 11;
    int k = kc * 32 + (lane >> 4) * 8 + j;
    int col = lane & 15;
    float v;
    if (ct < 8) {
      v = W1[k * 128 + ct * 16 + col];
    } else {
      int h = col & 7;
      const float* att = (col < 8) ? as1 : ad1;
      float s = 0.f;
      #pragma unroll
      for (int d = 0; d < 16; ++d) s += W1[k * 128 + h * 16 + d] * att[h * 16 + d];
      v = s;
    }
    unsigned u = __float_as_uint(v);
    unsigned hi = (u + 0x7FFFu + ((u >> 16) & 1u)) >> 16;
    float rem = v - __uint_as_float(hi << 16);
    unsigned ur = __float_as_uint(rem);
    unsigned lo = (ur + 0x7FFFu + ((ur >> 16) & 1u)) >> 16;
    whi[t] = (unsigned short)hi;
    wlo[t] = (unsigned short)lo;
  } else if (t < 18432 + 6144) {
    int u2 = t - 18432;
    int j = u2 & 7, lane = (u2 >> 3) & 63, kc = (u2 >> 9) & 3, ct = u2 >> 11;  // ct 0..2
    int k = kc * 32 + (lane >> 4) * 8 + j;
    int col = ct * 16 + (lane & 15);
    float v;
    if (col < OUT_DIM) {
      v = W2[k * OUT_DIM + col];
    } else if (col < 42) {
      const float* att = (col == OUT_DIM) ? as2 : ad2;
      float s = 0.f;
      #pragma unroll 8
      for (int d = 0; d < OUT_DIM; ++d) s += W2[k * OUT_DIM + d] * att[d];
      v = s;
    } else {
      v = 0.f;
    }
    w2p[u2] = f32_to_bf16_rne(v);
  }
}

// ---------------- GEMM1 via MFMA (split-bf16), fused a1s/a1d; h1 stored bf16 ----------------
__global__ __launch_bounds__(256) void gemm1_mfma_k(
    const float* __restrict__ x, const unsigned short* __restrict__ whi,
    const unsigned short* __restrict__ wlo,
    unsigned short* __restrict__ h1, float* __restrict__ a1s, float* __restrict__ a1d, int N) {
  int w = threadIdx.x >> 6, lane = threadIdx.x & 63;
  int quad = lane >> 4, l15 = lane & 15;
  int row = blockIdx.x * 64 + w * 16 + l15;
  int rowc = (row < N) ? row : (N - 1);

  f32x4 acc[9];
  #pragma unroll
  for (int t = 0; t < 9; ++t) acc[t] = (f32x4){0.f, 0.f, 0.f, 0.f};

  const float* xr = x + (size_t)rowc * 128 + quad * 8;
  #pragma unroll
  for (int kc = 0; kc < 4; ++kc) {
    f32x4 a0 = *reinterpret_cast<const f32x4*>(xr + kc * 32);
    f32x4 a1 = *reinterpret_cast<const f32x4*>(xr + kc * 32 + 4);
    float av[8] = {a0.x, a0.y, a0.z, a0.w, a1.x, a1.y, a1.z, a1.w};
    bf16x8 ahi, alo;
    #pragma unroll
    for (int j = 0; j < 8; ++j) {
      unsigned u = __float_as_uint(av[j]);
      unsigned hi = (u + 0x7FFFu + ((u >> 16) & 1u)) >> 16;
      float rem = av[j] - __uint_as_float(hi << 16);
      unsigned ur = __float_as_uint(rem);
      unsigned lo = (ur + 0x7FFFu + ((ur >> 16) & 1u)) >> 16;
      ahi[j] = (short)hi;
      alo[j] = (short)lo;
    }
    #pragma unroll
    for (int ct = 0; ct < 9; ++ct) {
      bf16x8 bh = *reinterpret_cast<const bf16x8*>(whi + ((size_t)(ct * 4 + kc) * 64 + lane) * 8);
      bf16x8 bl = *reinterpret_cast<const bf16x8*>(wlo + ((size_t)(ct * 4 + kc) * 64 + lane) * 8);
      acc[ct] = __builtin_amdgcn_mfma_f32_16x16x32_bf16(ahi, bh, acc[ct], 0, 0, 0);
      acc[ct] = __builtin_amdgcn_mfma_f32_16x16x32_bf16(ahi, bl, acc[ct], 0, 0, 0);
      acc[ct] = __builtin_amdgcn_mfma_f32_16x16x32_bf16(alo, bh, acc[ct], 0, 0, 0);
    }
  }
  int rbase = blockIdx.x * 64 + w * 16 + quad * 4;
  #pragma unroll
  for (int reg = 0; reg < 4; ++reg) {
    int r = rbase + reg;
    if (r < N) {
      #pragma unroll
      for (int ct = 0; ct < 8; ++ct)
        h1[(size_t)r * 128 + ct * 16 + l15] = f32_to_bf16_rne(acc[ct][reg]);
      float v = acc[8][reg];
      if (l15 < 8) a1s[r * 8 + l15] = v;
      else         a1d[r * 8 + (l15 - 8)] = v;
    }
  }
}

// ---------------- Layer-1 aggregation: wave-per-node, two-phase (LDS weight cache) ----------------
// Phase 1: 8 slots x 8 heads -> each (edge,head) weight computed once, cached in LDS.
// Phase 2: R5-style straight-line unroll-8 gather loop; w/s via broadcast LDS reads.
__global__ __launch_bounds__(256) void agg1_k(
    const int* __restrict__ row_ptr, const int* __restrict__ csr_src,
    const float* __restrict__ a1s, const float* __restrict__ a1d,
    const unsigned* __restrict__ h1u, const float* __restrict__ bias1,
    unsigned* __restrict__ vrowp, int N) {
  int wid = threadIdx.x >> 6;
  int lane = threadIdx.x & 63;
  int n = blockIdx.x * 4 + wid;

  __shared__ __align__(16) float wls_s[4][8 * 132];  // [wave][h*132 + idx] (pad 4 -> 2-way max on writes)
  __shared__ __align__(16) int   srcs_s[4][128];

  if (n >= N) return;
  float* wls  = wls_s[wid];
  int*   srcs = srcs_s[wid];

  int rs = row_ptr[n], re = row_ptr[n + 1];
  int deg = re - rs;
  int slot = lane >> 3, hw = lane & 7;
  float adn = a1d[n * 8 + hw];

  // phase 1: weights (raw exp) for first min(deg,128) edges; sw over all edges
  float sw = 0.f;
  for (int i0 = 0; i0 < deg; i0 += 8) {
    int idx = i0 + slot;
    bool val = idx < deg;
    int s = csr_src[rs + (val ? idx : deg - 1)];
    float e = a1s[s * 8 + hw] + adn;
    e = fmaxf(e, NEG * e);
    float w = val ? __expf(e) : 0.f;
    sw += w;
    if (val && idx < 128) {
      wls[hw * 132 + idx] = w;
      if (hw == 0) srcs[idx] = s;
    }
  }
  sw += __shfl_xor(sw, 8);
  sw += __shfl_xor(sw, 16);
  sw += __shfl_xor(sw, 32);
  int h = lane >> 3;
  float inv = __shfl(1.f / (sw + 1e-16f), h);  // lane h holds head h's total

  // phase 2: batched gathers, weights from LDS (broadcast reads, conflict-free)
  float accx = 0.f, accy = 0.f;
  int lim = (deg < 128) ? deg : 128;
  const float* wh = wls + h * 132;
  int i = 0;
  for (; i + 8 <= lim; i += 8) {
    int4 sa = *reinterpret_cast<const int4*>(srcs + i);
    int4 sb = *reinterpret_cast<const int4*>(srcs + i + 4);
    float4 wa = *reinterpret_cast<const float4*>(wh + i);
    float4 wb = *reinterpret_cast<const float4*>(wh + i + 4);
    unsigned u0 = h1u[(size_t)sa.x * 64 + lane];
    unsigned u1 = h1u[(size_t)sa.y * 64 + lane];
    unsigned u2 = h1u[(size_t)sa.z * 64 + lane];
    unsigned u3 = h1u[(size_t)sa.w * 64 + lane];
    unsigned u4 = h1u[(size_t)sb.x * 64 + lane];
    unsigned u5 = h1u[(size_t)sb.y * 64 + lane];
    unsigned u6 = h1u[(size_t)sb.z * 64 + lane];
    unsigned u7 = h1u[(size_t)sb.w * 64 + lane];
    accx += wa.x * __uint_as_float(u0 << 16) + wa.y * __uint_as_float(u1 << 16)
          + wa.z * __uint_as_float(u2 << 16) + wa.w * __uint_as_float(u3 << 16)
          + wb.x * __uint_as_float(u4 << 16) + wb.y * __uint_as_float(u5 << 16)
          + wb.z * __uint_as_float(u6 << 16) + wb.w * __uint_as_float(u7 << 16);
    accy += wa.x * __uint_as_float(u0 & 0xFFFF0000u) + wa.y * __uint_as_float(u1 & 0xFFFF0000u)
          + wa.z * __uint_as_float(u2 & 0xFFFF0000u) + wa.w * __uint_as_float(u3 & 0xFFFF0000u)
          + wb.x * __uint_as_float(u4 & 0xFFFF0000u) + wb.y * __uint_as_float(u5 & 0xFFFF0000u)
          + wb.z * __uint_as_float(u6 & 0xFFFF0000u) + wb.w * __uint_as_float(u7 & 0xFFFF0000u);
  }
  for (; i < lim; ++i) {
    int s = srcs[i];
    float w = wh[i];
    unsigned u = h1u[(size_t)s * 64 + lane];
    accx += w * __uint_as_float(u << 16);
    accy += w * __uint_as_float(u & 0xFFFF0000u);
  }
  if (deg > 128) {  // rare tail: recompute weights inline
    float adn2 = a1d[n * 8 + h];
    for (int j2 = 128; j2 < deg; ++j2) {
      int s = csr_src[rs + j2];
      float e = a1s[s * 8 + h] + adn2;
      e = fmaxf(e, NEG * e);
      float w = __expf(e);
      unsigned u = h1u[(size_t)s * 64 + lane];
      accx += w * __uint_as_float(u << 16);
      accy += w * __uint_as_float(u & 0xFFFF0000u);
    }
  }
  float2 b = *reinterpret_cast<const float2*>(bias1 + 2 * lane);
  float vx = accx * inv + b.x;
  float vy = accy * inv + b.y;
  vx = (vx > 0.f) ? vx : (__expf(vx) - 1.f);
  vy = (vy > 0.f) ? vy : (__expf(vy) - 1.f);
  unsigned packed = (unsigned)f32_to_bf16_rne(vx) | ((unsigned)f32_to_bf16_rne(vy) << 16);
  vrowp[(size_t)n * 64 + lane] = packed;
}

// ---------------- GEMM2 via MFMA: h2 = ELU(vrow) @ W2 (+ folded a2s/a2d cols) ----------------
__global__ __launch_bounds__(256) void gemm2_mfma_k(
    const unsigned short* __restrict__ vrow, const unsigned short* __restrict__ w2p,
    unsigned short* __restrict__ h2, float* __restrict__ a2s, float* __restrict__ a2d, int N) {
  int w = threadIdx.x >> 6, lane = threadIdx.x & 63;
  int quad = lane >> 4, l15 = lane & 15;
  int row = blockIdx.x * 64 + w * 16 + l15;
  int rowc = (row < N) ? row : (N - 1);

  f32x4 acc[3];
  #pragma unroll
  for (int t = 0; t < 3; ++t) acc[t] = (f32x4){0.f, 0.f, 0.f, 0.f};

  const unsigned short* vr = vrow + (size_t)rowc * 128 + quad * 8;
  #pragma unroll
  for (int kc = 0; kc < 4; ++kc) {
    bf16x8 a = *reinterpret_cast<const bf16x8*>(vr + kc * 32);
    #pragma unroll
    for (int ct = 0; ct < 3; ++ct) {
      bf16x8 bfrag = *reinterpret_cast<const bf16x8*>(w2p + ((size_t)(ct * 4 + kc) * 64 + lane) * 8);
      acc[ct] = __builtin_amdgcn_mfma_f32_16x16x32_bf16(a, bfrag, acc[ct], 0, 0, 0);
    }
  }
  int rbase = blockIdx.x * 64 + w * 16 + quad * 4;
  #pragma unroll
  for (int reg = 0; reg < 4; ++reg) {
    int r = rbase + reg;
    if (r < N) {
      #pragma unroll
      for (int ct = 0; ct < 3; ++ct) {
        int col = ct * 16 + l15;
        float v = acc[ct][reg];
        if (col < OUT_DIM)       h2[(size_t)r * 64 + col] = f32_to_bf16_rne(v);
        else if (col == OUT_DIM) a2s[r] = v;
        else if (col == 41)      a2d[r] = v;
      }
    }
  }
}

// ---------------- Layer-2 aggregation + log_softmax: two-phase (LDS weight cache) ----------------
__global__ __launch_bounds__(256) void agg2_k(
    const int* __restrict__ row_ptr, const int* __restrict__ csr_src,
    const float* __restrict__ a2s, const float* __restrict__ a2d,
    const unsigned short* __restrict__ h2, const float* __restrict__ bias2,
    float* __restrict__ out, int N) {
  int wid = threadIdx.x >> 6;
  int lane = threadIdx.x & 63;
  int n = blockIdx.x * 4 + wid;

  __shared__ __align__(16) float wls_s[4][128];
  __shared__ __align__(16) int   srcs_s[4][128];

  if (n >= N) return;
  float* wls  = wls_s[wid];
  int*   srcs = srcs_s[wid];

  int rs = row_ptr[n], re = row_ptr[n + 1];
  int deg = re - rs;
  float adn = a2d[n];

  // phase 1: one exp per edge per wave
  float sw = 0.f;
  for (int i0 = 0; i0 < deg; i0 += 64) {
    int idx = i0 + lane;
    bool val = idx < deg;
    int s = csr_src[rs + (val ? idx : deg - 1)];
    float e = a2s[s] + adn;
    e = fmaxf(e, NEG * e);
    float w = val ? __expf(e) : 0.f;
    sw += w;
    if (val && idx < 128) { wls[idx] = w; srcs[idx] = s; }
  }
  #pragma unroll
  for (int off = 32; off > 0; off >>= 1) sw += __shfl_xor(sw, off);
  float inv = 1.f / (sw + 1e-16f);

  bool act = lane < OUT_DIM;
  float acc = 0.f;
  int lim = (deg < 128) ? deg : 128;
  int i = 0;
  for (; i + 8 <= lim; i += 8) {
    int4 sa = *reinterpret_cast<const int4*>(srcs + i);
    int4 sb = *reinterpret_cast<const int4*>(srcs + i + 4);
    float4 wa = *reinterpret_cast<const float4*>(wls + i);
    float4 wb = *reinterpret_cast<const float4*>(wls + i + 4);
    unsigned g0 = h2[(size_t)sa.x * 64 + lane];
    unsigned g1 = h2[(size_t)sa.y * 64 + lane];
    unsigned g2 = h2[(size_t)sa.z * 64 + lane];
    unsigned g3 = h2[(size_t)sa.w * 64 + lane];
    unsigned g4 = h2[(size_t)sb.x * 64 + lane];
    unsigned g5 = h2[(size_t)sb.y * 64 + lane];
    unsigned g6 = h2[(size_t)sb.z * 64 + lane];
    unsigned g7 = h2[(size_t)sb.w * 64 + lane];
    acc += wa.x * __uint_as_float(g0 << 16) + wa.y * __uint_as_float(g1 << 16)
         + wa.z * __uint_as_float(g2 << 16) + wa.w * __uint_as_float(g3 << 16)
         + wb.x * __uint_as_float(g4 << 16) + wb.y * __uint_as_float(g5 << 16)
         + wb.z * __uint_as_float(g6 << 16) + wb.w * __uint_as_float(g7 << 16);
  }
  for (; i < lim; ++i) {
    int s = srcs[i];
    float w = wls[i];
    unsigned g = h2[(size_t)s * 64 + lane];
    acc += w * __uint_as_float(g << 16);
  }
  if (deg > 128) {  // rare tail: recompute weights inline
    for (int j2 = 128; j2 < deg; ++j2) {
      int s = csr_src[rs + j2];
      float e = a2s[s] + adn;
      e = fmaxf(e, NEG * e);
      float w = __expf(e);
      unsigned g = h2[(size_t)s * 64 + lane];
      acc += w * __uint_as_float(g << 16);
    }
  }
  float v = act ? (acc * inv + bias2[lane]) : -1e30f;
  float vm = v;
  #pragma unroll
  for (int off = 32; off > 0; off >>= 1) vm = fmaxf(vm, __shfl_xor(vm, off));
  float ex = act ? __expf(v - vm) : 0.f;
  float es = ex;
  #pragma unroll
  for (int off = 32; off > 0; off >>= 1) es += __shfl_xor(es, off);
  if (act) out[(size_t)n * OUT_DIM + lane] = v - vm - __logf(es);
}

// ---------------- launch ----------------

extern "C" void kernel_launch(void* const* d_in, const int* in_sizes, int n_in,
                              void* d_out, int out_size, void* d_ws, size_t ws_size,
                              hipStream_t stream) {
  const float* x   = (const float*)d_in[0];
  const float* W1  = (const float*)d_in[1];
  const float* as1 = (const float*)d_in[2];
  const float* ad1 = (const float*)d_in[3];
  const float* b1  = (const float*)d_in[4];
  const float* W2  = (const float*)d_in[5];
  const float* as2 = (const float*)d_in[6];
  const float* ad2 = (const float*)d_in[7];
  const float* b2  = (const float*)d_in[8];
  const int*   ei  = (const int*)d_in[9];
  int N  = in_sizes[0] / IN_DIM;
  int E0 = in_sizes[9] / 2;
  int EP = E0 + N;
  int snode = (N + NSLICE - 1) / NSLICE;
  float* out = (float*)d_out;

  char* ws = (char*)d_ws;
  size_t off = 0;
  auto alloc = [&](size_t bytes) {
    char* p = ws + off;
    off += (bytes + 255) & ~size_t(255);
    return p;
  };
  unsigned short* h1   = (unsigned short*)alloc((size_t)N * 128 * 2);
  float* a1s  = (float*)alloc((size_t)N * 8 * 4);
  float* a1d  = (float*)alloc((size_t)N * 8 * 4);
  unsigned*       vrow = (unsigned*)alloc((size_t)N * 64 * 4);   // N x 128 bf16 packed
  unsigned short* h2   = (unsigned short*)alloc((size_t)N * 64 * 2);
  float* a2s  = (float*)alloc((size_t)N * 4);
  float* a2d  = (float*)alloc((size_t)N * 4);
  int*   deg  = (int*)alloc((size_t)N * 4);
  int*   cnt  = (int*)alloc((size_t)N * 4);
  int*   rp   = (int*)alloc((size_t)(N + 4) * 4);
  int*   bsum = (int*)alloc((size_t)1024 * 4);
  int*   csr  = (int*)alloc((size_t)EP * 4);
  unsigned short* whi = (unsigned short*)alloc((size_t)18432 * 2);
  unsigned short* wlo = (unsigned short*)alloc((size_t)18432 * 2);
  unsigned short* w2p = (unsigned short*)alloc((size_t)6144 * 2);

  int nb = (N + 1023) / 1024;
  int nchunk = (EP + 255) / 256;
  prep_k<<<(N + 255) / 256, 256, 0, stream>>>(W1, as1, ad1, W2, as2, ad2, whi, wlo, w2p, deg, N);
  hist_k<<<nchunk * NSLICE, 256, 0, stream>>>(ei, E0, N, snode, deg);
  scanA_k<<<nb, 1024, 0, stream>>>(deg, rp, bsum, N);
  scanB_k<<<1, 1024, 0, stream>>>(bsum, nb, rp, N);
  scanC_k<<<nb, 1024, 0, stream>>>(rp, bsum, cnt, N);
  scatter_k<<<nchunk * NSLICE, 256, 0, stream>>>(ei, E0, N, snode, cnt, csr);
  gemm1_mfma_k<<<(N + 63) / 64, 256, 0, stream>>>(x, whi, wlo, h1, a1s, a1d, N);
  agg1_k<<<(N + 3) / 4, 256, 0, stream>>>(rp, csr, a1s, a1d, (const unsigned*)h1, b1, vrow, N);
  gemm2_mfma_k<<<(N + 63) / 64, 256, 0, stream>>>((const unsigned short*)vrow, w2p, h2, a2s, a2d, N);
  agg2_k<<<(N + 3) / 4, 256, 0, stream>>>(rp, csr, a2s, a2d, h2, b2, out, N);
}

// Round 12
// 258.003 us; speedup vs baseline: 1.1628x; 1.0466x over previous
//
#include <hip/hip_runtime.h>
#include <math.h>

#define IN_DIM 128
#define HEADS 8
#define HID 16
#define OUT_DIM 40
#define NEG 0.2f
#define NSLICE 8

typedef short bf16x8 __attribute__((ext_vector_type(8)));
typedef float f32x4 __attribute__((ext_vector_type(4)));

__device__ __forceinline__ unsigned short f32_to_bf16_rne(float v) {
  unsigned u = __float_as_uint(v);
  return (unsigned short)((u + 0x7FFFu + ((u >> 16) & 1u)) >> 16);
}

// ---------------- scan ----------------

__global__ __launch_bounds__(1024) void scanA_k(const int* __restrict__ deg, int* __restrict__ rp,
                                                int* __restrict__ bsum, int n) {
  __shared__ int wsum[16];
  int tid = threadIdx.x;
  int i = blockIdx.x * 1024 + tid;
  int lane = tid & 63, w = tid >> 6;
  int v = (i < n) ? deg[i] : 0;
  int x = v;
  #pragma unroll
  for (int off = 1; off < 64; off <<= 1) {
    int y = __shfl_up(x, off);
    if (lane >= off) x += y;
  }
  if (lane == 63) wsum[w] = x;
  __syncthreads();
  if (tid < 16) {
    int s = wsum[tid];
    #pragma unroll
    for (int off = 1; off < 16; off <<= 1) {
      int y = __shfl_up(s, off);
      if (tid >= off) s += y;
    }
    wsum[tid] = s;
  }
  __syncthreads();
  int woff = (w == 0) ? 0 : wsum[w - 1];
  if (i < n) rp[i] = woff + x - v;
  if (tid == 0) bsum[blockIdx.x] = wsum[15];
}

__global__ __launch_bounds__(1024) void scanB_k(int* __restrict__ bsum, int nb,
                                                int* __restrict__ rp, int n) {
  __shared__ int wsum[16];
  int tid = threadIdx.x;
  int lane = tid & 63, w = tid >> 6;
  int v = (tid < nb) ? bsum[tid] : 0;
  int x = v;
  #pragma unroll
  for (int off = 1; off < 64; off <<= 1) {
    int y = __shfl_up(x, off);
    if (lane >= off) x += y;
  }
  if (lane == 63) wsum[w] = x;
  __syncthreads();
  if (tid < 16) {
    int s = wsum[tid];
    #pragma unroll
    for (int off = 1; off < 16; off <<= 1) {
      int y = __shfl_up(s, off);
      if (tid >= off) s += y;
    }
    wsum[tid] = s;
  }
  __syncthreads();
  int woff = (w == 0) ? 0 : wsum[w - 1];
  if (tid < nb) bsum[tid] = woff + x - v;
  if (tid == 0) rp[n] = wsum[15];
}

__global__ __launch_bounds__(1024) void scanC_k(int* __restrict__ rp, const int* __restrict__ bsum,
                                                int* __restrict__ cnt, int n) {
  int i = blockIdx.x * 1024 + threadIdx.x;
  if (i < n) {
    int v = rp[i] + bsum[blockIdx.x];
    rp[i] = v;
    cnt[i] = v;
  }
}

__global__ void scatter_k(const int* __restrict__ ei, int E0, int N, int snode,
                          int* __restrict__ cnt, int* __restrict__ csr_src) {
  int b = blockIdx.x;
  int slice = b & (NSLICE - 1);
  int e = (b >> 3) * 256 + threadIdx.x;
  int EP = E0 + N;
  if (e >= EP) return;
  int d = (e < E0) ? ei[E0 + e] : (e - E0);
  if (d / snode != slice) return;
  int s = (e < E0) ? ei[e] : d;
  int pos = atomicAdd(&cnt[d], 1);
  csr_src[pos] = s;
}

// ---------------- prep: zero deg + pack W1 (hi/lo bf16) + pack W2 (bf16, folded att cols) ----------------
__global__ void prep_k(const float* __restrict__ W1, const float* __restrict__ as1,
                       const float* __restrict__ ad1, const float* __restrict__ W2,
                       const float* __restrict__ as2, const float* __restrict__ ad2,
                       unsigned short* __restrict__ whi, unsigned short* __restrict__ wlo,
                       unsigned short* __restrict__ w2p, int* __restrict__ deg, int N) {
  int t = blockIdx.x * 256 + threadIdx.x;
  if (t < N) deg[t] = 0;
  if (t < 18432) {
    int j = t & 7, lane = (t >> 3) & 63, kc = (t >> 9) & 3, ct = t >> 11;
    int k = kc * 32 + (lane >> 4) * 8 + j;
    int col = lane & 15;
    float v;
    if (ct < 8) {
      v = W1[k * 128 + ct * 16 + col];
    } else {
      int h = col & 7;
      const float* att = (col < 8) ? as1 : ad1;
      float s = 0.f;
      #pragma unroll
      for (int d = 0; d < 16; ++d) s += W1[k * 128 + h * 16 + d] * att[h * 16 + d];
      v = s;
    }
    unsigned u = __float_as_uint(v);
    unsigned hi = (u + 0x7FFFu + ((u >> 16) & 1u)) >> 16;
    float rem = v - __uint_as_float(hi << 16);
    unsigned ur = __float_as_uint(rem);
    unsigned lo = (ur + 0x7FFFu + ((ur >> 16) & 1u)) >> 16;
    whi[t] = (unsigned short)hi;
    wlo[t] = (unsigned short)lo;
  } else if (t < 18432 + 6144) {
    int u2 = t - 18432;
    int j = u2 & 7, lane = (u2 >> 3) & 63, kc = (u2 >> 9) & 3, ct = u2 >> 11;  // ct 0..2
    int k = kc * 32 + (lane >> 4) * 8 + j;
    int col = ct * 16 + (lane & 15);
    float v;
    if (col < OUT_DIM) {
      v = W2[k * OUT_DIM + col];
    } else if (col < 42) {
      const float* att = (col == OUT_DIM) ? as2 : ad2;
      float s = 0.f;
      #pragma unroll 8
      for (int d = 0; d < OUT_DIM; ++d) s += W2[k * OUT_DIM + d] * att[d];
      v = s;
    } else {
      v = 0.f;
    }
    w2p[u2] = f32_to_bf16_rne(v);
  }
}

// ---------------- fused: GEMM1 (MFMA, split-bf16) | hist (XCD-sliced) ----------------
// blocks [0, G1): gemm1 rows; blocks [G1, ...): histogram.
__global__ __launch_bounds__(256) void gemm1_hist_k(
    const float* __restrict__ x, const unsigned short* __restrict__ whi,
    const unsigned short* __restrict__ wlo,
    unsigned short* __restrict__ h1, float* __restrict__ a1s, float* __restrict__ a1d,
    int N, int G1,
    const int* __restrict__ ei, int E0, int snode, int* __restrict__ deg) {
  if ((int)blockIdx.x >= G1) {
    int b = blockIdx.x - G1;
    int slice = b & (NSLICE - 1);
    int e = (b >> 3) * 256 + threadIdx.x;
    int EP = E0 + N;
    if (e >= EP) return;
    int d = (e < E0) ? ei[E0 + e] : (e - E0);
    if (d / snode == slice) atomicAdd(&deg[d], 1);
    return;
  }
  int w = threadIdx.x >> 6, lane = threadIdx.x & 63;
  int quad = lane >> 4, l15 = lane & 15;
  int row = blockIdx.x * 64 + w * 16 + l15;
  int rowc = (row < N) ? row : (N - 1);

  f32x4 acc[9];
  #pragma unroll
  for (int t = 0; t < 9; ++t) acc[t] = (f32x4){0.f, 0.f, 0.f, 0.f};

  const float* xr = x + (size_t)rowc * 128 + quad * 8;
  #pragma unroll
  for (int kc = 0; kc < 4; ++kc) {
    f32x4 a0 = *reinterpret_cast<const f32x4*>(xr + kc * 32);
    f32x4 a1 = *reinterpret_cast<const f32x4*>(xr + kc * 32 + 4);
    float av[8] = {a0.x, a0.y, a0.z, a0.w, a1.x, a1.y, a1.z, a1.w};
    bf16x8 ahi, alo;
    #pragma unroll
    for (int j = 0; j < 8; ++j) {
      unsigned u = __float_as_uint(av[j]);
      unsigned hi = (u + 0x7FFFu + ((u >> 16) & 1u)) >> 16;
      float rem = av[j] - __uint_as_float(hi << 16);
      unsigned ur = __float_as_uint(rem);
      unsigned lo = (ur + 0x7FFFu + ((ur >> 16) & 1u)) >> 16;
      ahi[j] = (short)hi;
      alo[j] = (short)lo;
    }
    #pragma unroll
    for (int ct = 0; ct < 9; ++ct) {
      bf16x8 bh = *reinterpret_cast<const bf16x8*>(whi + ((size_t)(ct * 4 + kc) * 64 + lane) * 8);
      bf16x8 bl = *reinterpret_cast<const bf16x8*>(wlo + ((size_t)(ct * 4 + kc) * 64 + lane) * 8);
      acc[ct] = __builtin_amdgcn_mfma_f32_16x16x32_bf16(ahi, bh, acc[ct], 0, 0, 0);
      acc[ct] = __builtin_amdgcn_mfma_f32_16x16x32_bf16(ahi, bl, acc[ct], 0, 0, 0);
      acc[ct] = __builtin_amdgcn_mfma_f32_16x16x32_bf16(alo, bh, acc[ct], 0, 0, 0);
    }
  }
  int rbase = blockIdx.x * 64 + w * 16 + quad * 4;
  #pragma unroll
  for (int reg = 0; reg < 4; ++reg) {
    int r = rbase + reg;
    if (r < N) {
      #pragma unroll
      for (int ct = 0; ct < 8; ++ct)
        h1[(size_t)r * 128 + ct * 16 + l15] = f32_to_bf16_rne(acc[ct][reg]);
      float v = acc[8][reg];
      if (l15 < 8) a1s[r * 8 + l15] = v;
      else         a1d[r * 8 + (l15 - 8)] = v;
    }
  }
}

// ---------------- Layer-1 aggregation: wave-per-node, 3-phase, 16 gathers in flight ----------------
__global__ __launch_bounds__(256) void agg1_k(
    const int* __restrict__ row_ptr, const int* __restrict__ csr_src,
    const float* __restrict__ a1s, const float* __restrict__ a1d,
    const unsigned* __restrict__ h1u, const float* __restrict__ bias1,
    unsigned* __restrict__ vrowp, int N) {
  int wid = threadIdx.x >> 6;
  int lane = threadIdx.x & 63;
  int n = blockIdx.x * 4 + wid;

  __shared__ __align__(16) float wls_s[4][8 * 132];
  __shared__ __align__(16) int   srcs_s[4][128];

  if (n >= N) return;
  float* wls  = wls_s[wid];
  int*   srcs = srcs_s[wid];

  int rs = row_ptr[n], re = row_ptr[n + 1];
  int deg = re - rs;
  int h = lane >> 3;

  float accx = 0.f, accy = 0.f, inv;

  if (deg <= 128) {
    // phase 0: bulk csr -> LDS (independent loads)
    for (int i0 = lane; i0 < deg; i0 += 64) srcs[i0] = csr_src[rs + i0];
    // phase 1: weights, 2 a1s gathers in flight; each (edge,head) exp once
    int slot = lane >> 3, hw = lane & 7;
    float adn = a1d[n * 8 + hw];
    float sw = 0.f;
    for (int i0 = 0; i0 < deg; i0 += 16) {
      int ia = i0 + slot, ib = i0 + 8 + slot;
      bool va = ia < deg, vb = ib < deg;
      int sa = srcs[va ? ia : 0];
      int sb = srcs[vb ? ib : 0];
      float ea = a1s[sa * 8 + hw] + adn;
      float eb = a1s[sb * 8 + hw] + adn;
      ea = fmaxf(ea, NEG * ea);
      eb = fmaxf(eb, NEG * eb);
      float wa = va ? __expf(ea) : 0.f;
      float wb = vb ? __expf(eb) : 0.f;
      sw += wa + wb;
      if (va) wls[hw * 132 + ia] = wa;
      if (vb) wls[hw * 132 + ib] = wb;
    }
    sw += __shfl_xor(sw, 8);
    sw += __shfl_xor(sw, 16);
    sw += __shfl_xor(sw, 32);
    inv = __shfl(1.f / (sw + 1e-16f), h);  // lane h holds head h's total

    // phase 2: 16 gathers in flight, w/s from LDS broadcast
    const float* wh = wls + h * 132;
    int i = 0;
    for (; i + 16 <= deg; i += 16) {
      int4 sa = *reinterpret_cast<const int4*>(srcs + i);
      int4 sb = *reinterpret_cast<const int4*>(srcs + i + 4);
      int4 sc = *reinterpret_cast<const int4*>(srcs + i + 8);
      int4 sd = *reinterpret_cast<const int4*>(srcs + i + 12);
      float4 wa = *reinterpret_cast<const float4*>(wh + i);
      float4 wb = *reinterpret_cast<const float4*>(wh + i + 4);
      float4 wc = *reinterpret_cast<const float4*>(wh + i + 8);
      float4 wd = *reinterpret_cast<const float4*>(wh + i + 12);
      unsigned u0 = h1u[(size_t)sa.x * 64 + lane];
      unsigned u1 = h1u[(size_t)sa.y * 64 + lane];
      unsigned u2 = h1u[(size_t)sa.z * 64 + lane];
      unsigned u3 = h1u[(size_t)sa.w * 64 + lane];
      unsigned u4 = h1u[(size_t)sb.x * 64 + lane];
      unsigned u5 = h1u[(size_t)sb.y * 64 + lane];
      unsigned u6 = h1u[(size_t)sb.z * 64 + lane];
      unsigned u7 = h1u[(size_t)sb.w * 64 + lane];
      unsigned u8 = h1u[(size_t)sc.x * 64 + lane];
      unsigned u9 = h1u[(size_t)sc.y * 64 + lane];
      unsigned uA = h1u[(size_t)sc.z * 64 + lane];
      unsigned uB = h1u[(size_t)sc.w * 64 + lane];
      unsigned uC = h1u[(size_t)sd.x * 64 + lane];
      unsigned uD = h1u[(size_t)sd.y * 64 + lane];
      unsigned uE = h1u[(size_t)sd.z * 64 + lane];
      unsigned uF = h1u[(size_t)sd.w * 64 + lane];
      accx += wa.x * __uint_as_float(u0 << 16) + wa.y * __uint_as_float(u1 << 16)
            + wa.z * __uint_as_float(u2 << 16) + wa.w * __uint_as_float(u3 << 16)
            + wb.x * __uint_as_float(u4 << 16) + wb.y * __uint_as_float(u5 << 16)
            + wb.z * __uint_as_float(u6 << 16) + wb.w * __uint_as_float(u7 << 16)
            + wc.x * __uint_as_float(u8 << 16) + wc.y * __uint_as_float(u9 << 16)
            + wc.z * __uint_as_float(uA << 16) + wc.w * __uint_as_float(uB << 16)
            + wd.x * __uint_as_float(uC << 16) + wd.y * __uint_as_float(uD << 16)
            + wd.z * __uint_as_float(uE << 16) + wd.w * __uint_as_float(uF << 16);
      accy += wa.x * __uint_as_float(u0 & 0xFFFF0000u) + wa.y * __uint_as_float(u1 & 0xFFFF0000u)
            + wa.z * __uint_as_float(u2 & 0xFFFF0000u) + wa.w * __uint_as_float(u3 & 0xFFFF0000u)
            + wb.x * __uint_as_float(u4 & 0xFFFF0000u) + wb.y * __uint_as_float(u5 & 0xFFFF0000u)
            + wb.z * __uint_as_float(u6 & 0xFFFF0000u) + wb.w * __uint_as_float(u7 & 0xFFFF0000u)
            + wc.x * __uint_as_float(u8 & 0xFFFF0000u) + wc.y * __uint_as_float(u9 & 0xFFFF0000u)
            + wc.z * __uint_as_float(uA & 0xFFFF0000u) + wc.w * __uint_as_float(uB & 0xFFFF0000u)
            + wd.x * __uint_as_float(uC & 0xFFFF0000u) + wd.y * __uint_as_float(uD & 0xFFFF0000u)
            + wd.z * __uint_as_float(uE & 0xFFFF0000u) + wd.w * __uint_as_float(uF & 0xFFFF0000u);
    }
    for (; i + 4 <= deg; i += 4) {
      int4 sa = *reinterpret_cast<const int4*>(srcs + i);
      float4 wa = *reinterpret_cast<const float4*>(wh + i);
      unsigned u0 = h1u[(size_t)sa.x * 64 + lane];
      unsigned u1 = h1u[(size_t)sa.y * 64 + lane];
      unsigned u2 = h1u[(size_t)sa.z * 64 + lane];
      unsigned u3 = h1u[(size_t)sa.w * 64 + lane];
      accx += wa.x * __uint_as_float(u0 << 16) + wa.y * __uint_as_float(u1 << 16)
            + wa.z * __uint_as_float(u2 << 16) + wa.w * __uint_as_float(u3 << 16);
      accy += wa.x * __uint_as_float(u0 & 0xFFFF0000u) + wa.y * __uint_as_float(u1 & 0xFFFF0000u)
            + wa.z * __uint_as_float(u2 & 0xFFFF0000u) + wa.w * __uint_as_float(u3 & 0xFFFF0000u);
    }
    for (; i < deg; ++i) {
      int s = srcs[i];
      float w = wh[i];
      unsigned u = h1u[(size_t)s * 64 + lane];
      accx += w * __uint_as_float(u << 16);
      accy += w * __uint_as_float(u & 0xFFFF0000u);
    }
  } else {
    // slow path (never hit at mean deg ~17): inline weights, R5-style
    float adn = a1d[n * 8 + h];
    float sw = 0.f;
    for (int i = rs; i < re; ++i) {
      int s = csr_src[i];
      float e = a1s[s * 8 + h] + adn;
      e = fmaxf(e, NEG * e);
      float w = __expf(e);
      unsigned u = h1u[(size_t)s * 64 + lane];
      sw += w;
      accx += w * __uint_as_float(u << 16);
      accy += w * __uint_as_float(u & 0xFFFF0000u);
    }
    inv = 1.f / (sw + 1e-16f);
  }

  float2 b = *reinterpret_cast<const float2*>(bias1 + 2 * lane);
  float vx = accx * inv + b.x;
  float vy = accy * inv + b.y;
  vx = (vx > 0.f) ? vx : (__expf(vx) - 1.f);
  vy = (vy > 0.f) ? vy : (__expf(vy) - 1.f);
  unsigned packed = (unsigned)f32_to_bf16_rne(vx) | ((unsigned)f32_to_bf16_rne(vy) << 16);
  vrowp[(size_t)n * 64 + lane] = packed;
}

// ---------------- GEMM2 via MFMA: h2 = ELU(vrow) @ W2 (+ folded a2s/a2d cols) ----------------
__global__ __launch_bounds__(256) void gemm2_mfma_k(
    const unsigned short* __restrict__ vrow, const unsigned short* __restrict__ w2p,
    unsigned short* __restrict__ h2, float* __restrict__ a2s, float* __restrict__ a2d, int N) {
  int w = threadIdx.x >> 6, lane = threadIdx.x & 63;
  int quad = lane >> 4, l15 = lane & 15;
  int row = blockIdx.x * 64 + w * 16 + l15;
  int rowc = (row < N) ? row : (N - 1);

  f32x4 acc[3];
  #pragma unroll
  for (int t = 0; t < 3; ++t) acc[t] = (f32x4){0.f, 0.f, 0.f, 0.f};

  const unsigned short* vr = vrow + (size_t)rowc * 128 + quad * 8;
  #pragma unroll
  for (int kc = 0; kc < 4; ++kc) {
    bf16x8 a = *reinterpret_cast<const bf16x8*>(vr + kc * 32);
    #pragma unroll
    for (int ct = 0; ct < 3; ++ct) {
      bf16x8 bfrag = *reinterpret_cast<const bf16x8*>(w2p + ((size_t)(ct * 4 + kc) * 64 + lane) * 8);
      acc[ct] = __builtin_amdgcn_mfma_f32_16x16x32_bf16(a, bfrag, acc[ct], 0, 0, 0);
    }
  }
  int rbase = blockIdx.x * 64 + w * 16 + quad * 4;
  #pragma unroll
  for (int reg = 0; reg < 4; ++reg) {
    int r = rbase + reg;
    if (r < N) {
      #pragma unroll
      for (int ct = 0; ct < 3; ++ct) {
        int col = ct * 16 + l15;
        float v = acc[ct][reg];
        if (col < OUT_DIM)       h2[(size_t)r * 64 + col] = f32_to_bf16_rne(v);
        else if (col == OUT_DIM) a2s[r] = v;
        else if (col == 41)      a2d[r] = v;
      }
    }
  }
}

// ---------------- Layer-2 aggregation + log_softmax: 3-phase, 16 gathers in flight ----------------
__global__ __launch_bounds__(256) void agg2_k(
    const int* __restrict__ row_ptr, const int* __restrict__ csr_src,
    const float* __restrict__ a2s, const float* __restrict__ a2d,
    const unsigned short* __restrict__ h2, const float* __restrict__ bias2,
    float* __restrict__ out, int N) {
  int wid = threadIdx.x >> 6;
  int lane = threadIdx.x & 63;
  int n = blockIdx.x * 4 + wid;

  __shared__ __align__(16) float wls_s[4][128];
  __shared__ __align__(16) int   srcs_s[4][128];

  if (n >= N) return;
  float* wls  = wls_s[wid];
  int*   srcs = srcs_s[wid];

  int rs = row_ptr[n], re = row_ptr[n + 1];
  int deg = re - rs;
  float adn = a2d[n];
  bool act = lane < OUT_DIM;
  float acc = 0.f, inv;

  if (deg <= 128) {
    for (int i0 = lane; i0 < deg; i0 += 64) srcs[i0] = csr_src[rs + i0];
    // phase 1: both batches' gathers in flight
    int ia = lane, ib = lane + 64;
    bool va = ia < deg, vb = ib < deg;
    int sa = srcs[va ? ia : 0];
    int sb = srcs[vb ? ib : 0];
    float ea = a2s[sa] + adn;
    float eb = a2s[sb] + adn;
    ea = fmaxf(ea, NEG * ea);
    eb = fmaxf(eb, NEG * eb);
    float wa = va ? __expf(ea) : 0.f;
    float wb = vb ? __expf(eb) : 0.f;
    float sw = wa + wb;
    if (va) wls[ia] = wa;
    if (vb) wls[ib] = wb;
    #pragma unroll
    for (int off = 32; off > 0; off >>= 1) sw += __shfl_xor(sw, off);
    inv = 1.f / (sw + 1e-16f);

    int i = 0;
    for (; i + 16 <= deg; i += 16) {
      int4 s0 = *reinterpret_cast<const int4*>(srcs + i);
      int4 s1 = *reinterpret_cast<const int4*>(srcs + i + 4);
      int4 s2 = *reinterpret_cast<const int4*>(srcs + i + 8);
      int4 s3 = *reinterpret_cast<const int4*>(srcs + i + 12);
      float4 w0 = *reinterpret_cast<const float4*>(wls + i);
      float4 w1 = *reinterpret_cast<const float4*>(wls + i + 4);
      float4 w2 = *reinterpret_cast<const float4*>(wls + i + 8);
      float4 w3 = *reinterpret_cast<const float4*>(wls + i + 12);
      unsigned g0 = h2[(size_t)s0.x * 64 + lane];
      unsigned g1 = h2[(size_t)s0.y * 64 + lane];
      unsigned g2 = h2[(size_t)s0.z * 64 + lane];
      unsigned g3 = h2[(size_t)s0.w * 64 + lane];
      unsigned g4 = h2[(size_t)s1.x * 64 + lane];
      unsigned g5 = h2[(size_t)s1.y * 64 + lane];
      unsigned g6 = h2[(size_t)s1.z * 64 + lane];
      unsigned g7 = h2[(size_t)s1.w * 64 + lane];
      unsigned g8 = h2[(size_t)s2.x * 64 + lane];
      unsigned g9 = h2[(size_t)s2.y * 64 + lane];
      unsigned gA = h2[(size_t)s2.z * 64 + lane];
      unsigned gB = h2[(size_t)s2.w * 64 + lane];
      unsigned gC = h2[(size_t)s3.x * 64 + lane];
      unsigned gD = h2[(size_t)s3.y * 64 + lane];
      unsigned gE = h2[(size_t)s3.z * 64 + lane];
      unsigned gF = h2[(size_t)s3.w * 64 + lane];
      acc += w0.x * __uint_as_float(g0 << 16) + w0.y * __uint_as_float(g1 << 16)
           + w0.z * __uint_as_float(g2 << 16) + w0.w * __uint_as_float(g3 << 16)
           + w1.x * __uint_as_float(g4 << 16) + w1.y * __uint_as_float(g5 << 16)
           + w1.z * __uint_as_float(g6 << 16) + w1.w * __uint_as_float(g7 << 16)
           + w2.x * __uint_as_float(g8 << 16) + w2.y * __uint_as_float(g9 << 16)
           + w2.z * __uint_as_float(gA << 16) + w2.w * __uint_as_float(gB << 16)
           + w3.x * __uint_as_float(gC << 16) + w3.y * __uint_as_float(gD << 16)
           + w3.z * __uint_as_float(gE << 16) + w3.w * __uint_as_float(gF << 16);
    }
    for (; i + 4 <= deg; i += 4) {
      int4 s0 = *reinterpret_cast<const int4*>(srcs + i);
      float4 w0 = *reinterpret_cast<const float4*>(wls + i);
      unsigned g0 = h2[(size_t)s0.x * 64 + lane];
      unsigned g1 = h2[(size_t)s0.y * 64 + lane];
      unsigned g2 = h2[(size_t)s0.z * 64 + lane];
      unsigned g3 = h2[(size_t)s0.w * 64 + lane];
      acc += w0.x * __uint_as_float(g0 << 16) + w0.y * __uint_as_float(g1 << 16)
           + w0.z * __uint_as_float(g2 << 16) + w0.w * __uint_as_float(g3 << 16);
    }
    for (; i < deg; ++i) {
      int s = srcs[i];
      float w = wls[i];
      unsigned g = h2[(size_t)s * 64 + lane];
      acc += w * __uint_as_float(g << 16);
    }
  } else {
    float sw = 0.f;
    for (int i = rs; i < re; ++i) {
      int s = csr_src[i];
      float e = a2s[s] + adn;
      e = fmaxf(e, NEG * e);
      float w = __expf(e);
      sw += w;
      unsigned g = h2[(size_t)s * 64 + lane];
      acc += w * __uint_as_float(g << 16);
    }
    inv = 1.f / (sw + 1e-16f);
  }

  float v = act ? (acc * inv + bias2[lane]) : -1e30f;
  float vm = v;
  #pragma unroll
  for (int off = 32; off > 0; off >>= 1) vm = fmaxf(vm, __shfl_xor(vm, off));
  float ex = act ? __expf(v - vm) : 0.f;
  float es = ex;
  #pragma unroll
  for (int off = 32; off > 0; off >>= 1) es += __shfl_xor(es, off);
  if (act) out[(size_t)n * OUT_DIM + lane] = v - vm - __logf(es);
}

// ---------------- launch ----------------

extern "C" void kernel_launch(void* const* d_in, const int* in_sizes, int n_in,
                              void* d_out, int out_size, void* d_ws, size_t ws_size,
                              hipStream_t stream) {
  const float* x   = (const float*)d_in[0];
  const float* W1  = (const float*)d_in[1];
  const float* as1 = (const float*)d_in[2];
  const float* ad1 = (const float*)d_in[3];
  const float* b1  = (const float*)d_in[4];
  const float* W2  = (const float*)d_in[5];
  const float* as2 = (const float*)d_in[6];
  const float* ad2 = (const float*)d_in[7];
  const float* b2  = (const float*)d_in[8];
  const int*   ei  = (const int*)d_in[9];
  int N  = in_sizes[0] / IN_DIM;
  int E0 = in_sizes[9] / 2;
  int EP = E0 + N;
  int snode = (N + NSLICE - 1) / NSLICE;
  float* out = (float*)d_out;

  char* ws = (char*)d_ws;
  size_t off = 0;
  auto alloc = [&](size_t bytes) {
    char* p = ws + off;
    off += (bytes + 255) & ~size_t(255);
    return p;
  };
  unsigned short* h1   = (unsigned short*)alloc((size_t)N * 128 * 2);
  float* a1s  = (float*)alloc((size_t)N * 8 * 4);
  float* a1d  = (float*)alloc((size_t)N * 8 * 4);
  unsigned*       vrow = (unsigned*)alloc((size_t)N * 64 * 4);   // N x 128 bf16 packed
  unsigned short* h2   = (unsigned short*)alloc((size_t)N * 64 * 2);
  float* a2s  = (float*)alloc((size_t)N * 4);
  float* a2d  = (float*)alloc((size_t)N * 4);
  int*   deg  = (int*)alloc((size_t)N * 4);
  int*   cnt  = (int*)alloc((size_t)N * 4);
  int*   rp   = (int*)alloc((size_t)(N + 4) * 4);
  int*   bsum = (int*)alloc((size_t)1024 * 4);
  int*   csr  = (int*)alloc((size_t)EP * 4);
  unsigned short* whi = (unsigned short*)alloc((size_t)18432 * 2);
  unsigned short* wlo = (unsigned short*)alloc((size_t)18432 * 2);
  unsigned short* w2p = (unsigned short*)alloc((size_t)6144 * 2);

  int nb = (N + 1023) / 1024;
  int nchunk = (EP + 255) / 256;
  int G1 = (N + 63) / 64;
  prep_k<<<(N + 255) / 256, 256, 0, stream>>>(W1, as1, ad1, W2, as2, ad2, whi, wlo, w2p, deg, N);
  gemm1_hist_k<<<G1 + nchunk * NSLICE, 256, 0, stream>>>(x, whi, wlo, h1, a1s, a1d, N, G1,
                                                         ei, E0, snode, deg);
  scanA_k<<<nb, 1024, 0, stream>>>(deg, rp, bsum, N);
  scanB_k<<<1, 1024, 0, stream>>>(bsum, nb, rp, N);
  scanC_k<<<nb, 1024, 0, stream>>>(rp, bsum, cnt, N);
  scatter_k<<<nchunk * NSLICE, 256, 0, stream>>>(ei, E0, N, snode, cnt, csr);
  agg1_k<<<(N + 3) / 4, 256, 0, stream>>>(rp, csr, a1s, a1d, (const unsigned*)h1, b1, vrow, N);
  gemm2_mfma_k<<<(N + 63) / 64, 256, 0, stream>>>((const unsigned short*)vrow, w2p, h2, a2s, a2d, N);
  agg2_k<<<(N + 3) / 4, 256, 0, stream>>>(rp, csr, a2s, a2d, h2, b2, out, N);
}